// Round 1
// baseline (9425.758 us; speedup 1.0000x reference)
//
#include <hip/hip_runtime.h>

// DynamicGraphAttention: B=16, L=256, D=128, F_IN=64, F_OUT=64
// One block per (b,l). Phases:
//   A: Wh = h @ W            (128x64 = 128x64 @ 64x64)
//   B: e_i = Wh@a1, e_j = Wh@a2
//   C: p(i,j) = adj ? exp(leakyrelu(e_i+e_j)) : 0  (no max-sub; logits bounded)
//      h_prime = (P @ Wh) / rowsum(P)
constexpr int D_   = 128;
constexpr int FIN  = 64;
constexpr int FOUT = 64;
constexpr float ALPHA = 0.2f;
constexpr int HT_STRIDE = 132;   // h^T [f][row] stride: 132 = 4*33 -> b128-aligned, conflict-free

__global__ __launch_bounds__(256, 3) void gat_kernel(
    const float* __restrict__ hg, const int* __restrict__ adjg,
    const float* __restrict__ Wg, const float* __restrict__ ag,
    float* __restrict__ outg)
{
    // sHWh: first holds h^T (64 x 128, stride 132 = 8448 floats), then Wh (128 x 64, stride 64)
    __shared__ float sHWh[FIN * HT_STRIDE];           // 33792 B
    // sWP: first holds W (64x64), then P-tile [j'(0..31)][row(0..127)]
    __shared__ float sWP[32 * 128];                   // 16384 B
    __shared__ float sEi[D_], sEj[D_], sL[D_];        // 1536 B
    __shared__ float sA[2 * FOUT];                    // 512 B
    // total ~52 KB -> 3 blocks/CU

    const int tid = threadIdx.x;
    const long bl = blockIdx.x;
    const float* hp   = hg   + bl * (long)(D_ * FIN);
    const int*   adjp = adjg + bl * (long)(D_ * D_);
    float*       outp = outg + bl * (long)(D_ * FOUT);

    // ---------------- stage W, a, h^T ----------------
    {
        const float4* W4 = (const float4*)Wg;
        float4* sW4 = (float4*)sWP;
        #pragma unroll
        for (int k = 0; k < 4; ++k) sW4[tid + 256 * k] = W4[tid + 256 * k];
        if (tid < 2 * FOUT) sA[tid] = ag[tid];
        const float4* h4 = (const float4*)hp;
        #pragma unroll
        for (int k = 0; k < 8; ++k) {
            int idx = tid + 256 * k;          // float4 index in [0,2048)
            float4 v = h4[idx];
            int row = idx >> 4;               // 16 float4 per 64-float row
            int f   = (idx & 15) << 2;
            sHWh[(f + 0) * HT_STRIDE + row] = v.x;
            sHWh[(f + 1) * HT_STRIDE + row] = v.y;
            sHWh[(f + 2) * HT_STRIDE + row] = v.z;
            sHWh[(f + 3) * HT_STRIDE + row] = v.w;
        }
    }
    __syncthreads();

    // ---------------- phase A: Wh = h @ W, 4x8 register tile ----------------
    const int rg = tid >> 3;      // 0..31 (4 rows each)
    const int cg = tid & 7;       // 0..7  (8 cols each)
    float acc[4][8];
    #pragma unroll
    for (int r = 0; r < 4; ++r)
        #pragma unroll
        for (int c = 0; c < 8; ++c) acc[r][c] = 0.f;

    for (int f = 0; f < FIN; ++f) {
        float4 hv = *(const float4*)&sHWh[f * HT_STRIDE + rg * 4];
        float4 w0 = *(const float4*)&sWP[f * 64 + cg * 8];
        float4 w1 = *(const float4*)&sWP[f * 64 + cg * 8 + 4];
        float hr[4] = {hv.x, hv.y, hv.z, hv.w};
        float wc[8] = {w0.x, w0.y, w0.z, w0.w, w1.x, w1.y, w1.z, w1.w};
        #pragma unroll
        for (int r = 0; r < 4; ++r)
            #pragma unroll
            for (int c = 0; c < 8; ++c)
                acc[r][c] += hr[r] * wc[c];
    }
    __syncthreads();   // all h/W reads complete

    // write Wh into sHWh (row-major, stride 64), overwriting h^T
    #pragma unroll
    for (int r = 0; r < 4; ++r) {
        float4 v0 = make_float4(acc[r][0], acc[r][1], acc[r][2], acc[r][3]);
        float4 v1 = make_float4(acc[r][4], acc[r][5], acc[r][6], acc[r][7]);
        *(float4*)&sHWh[(rg * 4 + r) * 64 + cg * 8]     = v0;
        *(float4*)&sHWh[(rg * 4 + r) * 64 + cg * 8 + 4] = v1;
    }
    __syncthreads();

    // ---------------- phase B: e_i, e_j ----------------
    if (tid < D_) {
        float ei = 0.f, ej = 0.f;
        #pragma unroll
        for (int o = 0; o < FOUT; o += 4) {
            float4 wv = *(const float4*)&sHWh[tid * 64 + o];
            float4 a1 = *(const float4*)&sA[o];
            float4 a2 = *(const float4*)&sA[FOUT + o];
            ei += wv.x * a1.x + wv.y * a1.y + wv.z * a1.z + wv.w * a1.w;
            ej += wv.x * a2.x + wv.y * a2.y + wv.z * a2.z + wv.w * a2.w;
        }
        sEi[tid] = ei;
        sEj[tid] = ej;
        sL[tid]  = 0.f;
    }
    __syncthreads();

    // ---------------- phase C: masked-softmax @ Wh, tiled over j ----------------
    #pragma unroll
    for (int r = 0; r < 4; ++r)
        #pragma unroll
        for (int c = 0; c < 8; ++c) acc[r][c] = 0.f;

    const int pi = tid >> 1;            // row for p-build
    const int pj = (tid & 1) << 4;      // 16-j segment within tile

    for (int t4 = 0; t4 < 4; ++t4) {
        const int j0 = t4 * 32;
        // build P-tile: sWP[j'][row], j' in [0,32)
        {
            const float ei = sEi[pi];
            float lp = 0.f;
            const int4* arow = (const int4*)&adjp[pi * D_ + j0 + pj];
            #pragma unroll
            for (int q = 0; q < 4; ++q) {
                int4 av = arow[q];
                int aa[4] = {av.x, av.y, av.z, av.w};
                #pragma unroll
                for (int k = 0; k < 4; ++k) {
                    int j = pj + q * 4 + k;                 // local j' in [0,32)
                    float e = ei + sEj[j0 + j];
                    e = e > 0.f ? e : ALPHA * e;
                    float p = (aa[k] > 0) ? __expf(e) : 0.f;
                    sWP[j * 128 + pi] = p;
                    lp += p;
                }
            }
            lp += __shfl_xor(lp, 1);
            if ((tid & 1) == 0) sL[pi] += lp;
        }
        __syncthreads();
        // accumulate: acc[r][c] += P[jj][rg*4+r] * Wh[j0+jj][cg*8+c]
        for (int jj = 0; jj < 32; ++jj) {
            float4 w0 = *(const float4*)&sHWh[(j0 + jj) * 64 + cg * 8];
            float4 w1 = *(const float4*)&sHWh[(j0 + jj) * 64 + cg * 8 + 4];
            float4 pv = *(const float4*)&sWP[jj * 128 + rg * 4];
            float pr[4] = {pv.x, pv.y, pv.z, pv.w};
            float wc[8] = {w0.x, w0.y, w0.z, w0.w, w1.x, w1.y, w1.z, w1.w};
            #pragma unroll
            for (int r = 0; r < 4; ++r)
                #pragma unroll
                for (int c = 0; c < 8; ++c)
                    acc[r][c] += pr[r] * wc[c];
        }
        __syncthreads();
    }

    // ---------------- epilogue: divide by row sum, write out ----------------
    #pragma unroll
    for (int r = 0; r < 4; ++r) {
        float inv = 1.0f / sL[rg * 4 + r];
        float4 v0 = make_float4(acc[r][0] * inv, acc[r][1] * inv,
                                acc[r][2] * inv, acc[r][3] * inv);
        float4 v1 = make_float4(acc[r][4] * inv, acc[r][5] * inv,
                                acc[r][6] * inv, acc[r][7] * inv);
        *(float4*)&outp[(rg * 4 + r) * 64 + cg * 8]     = v0;
        *(float4*)&outp[(rg * 4 + r) * 64 + cg * 8 + 4] = v1;
    }
}

extern "C" void kernel_launch(void* const* d_in, const int* in_sizes, int n_in,
                              void* d_out, int out_size, void* d_ws, size_t ws_size,
                              hipStream_t stream) {
    const float* h   = (const float*)d_in[0];
    const int*   adj = (const int*)d_in[1];
    const float* W   = (const float*)d_in[2];
    const float* a   = (const float*)d_in[3];
    float*       out = (float*)d_out;
    gat_kernel<<<dim3(16 * 256), dim3(256), 0, stream>>>(h, adj, W, a, out);
}

// Round 4
// 538.958 us; speedup vs baseline: 17.4889x; 17.4889x over previous
//
#include <hip/hip_runtime.h>

// DynamicGraphAttention: B=16, L=256, D=128, F_IN=64, F_OUT=64
// One block per (b,l). v4 = v3 with phase-B dot-product fixed (was covering
// only o<32). bf16 LDS staging of hT and Wh (35.8KB -> 4 blocks/CU).
constexpr int D_   = 128;
constexpr int FIN  = 64;
constexpr int FOUT = 64;
constexpr float ALPHA = 0.2f;
constexpr int HT_S = 136;   // hT [f][row] stride in ushorts; byte stride 272 (8B-aligned reads)

static __device__ __forceinline__ unsigned short f2bf(float x) {
    unsigned u = __float_as_uint(x);
    unsigned r = (u + 0x7fffu + ((u >> 16) & 1u)) >> 16;   // RNE, finite inputs
    return (unsigned short)r;
}
static __device__ __forceinline__ unsigned pack2(float a, float b) {
    return (unsigned)f2bf(a) | ((unsigned)f2bf(b) << 16);
}
#define BFLO(u) __uint_as_float((u) << 16)
#define BFHI(u) __uint_as_float((u) & 0xffff0000u)

__global__ __launch_bounds__(256, 4) void gat_kernel(
    const float* __restrict__ hg, const int* __restrict__ adjg,
    const float* __restrict__ Wg, const float* __restrict__ ag,
    float* __restrict__ outg)
{
    // sHT: hT bf16 [f][row] (64 x 136 ushorts, 17408B); reused as Wh bf16 [row][o] stride 64
    __shared__ unsigned short sHT[FIN * HT_S];
    // sP: W fp32 [f][o] (64x64) during phase A; P-tile [j'(0..31)][row] in phase C (16384B)
    __shared__ float sP[32 * 128];
    __shared__ float sEi[D_], sEj[D_], sL[D_];
    __shared__ float sA[2 * FOUT];
    // total 35840 B -> 4 blocks/CU

    const int tid = threadIdx.x;
    const long bl = blockIdx.x;
    const float* hp   = hg   + bl * (long)(D_ * FIN);
    const int*   adjp = adjg + bl * (long)(D_ * D_);
    float*       outp = outg + bl * (long)(D_ * FOUT);

    // ---------------- stage: W -> sP (fp32), a -> sA, hT -> sHT (bf16 transpose) ----------------
    {
        const float4* W4 = (const float4*)Wg;
        float4* sW4 = (float4*)sP;
        #pragma unroll
        for (int k = 0; k < 4; ++k) sW4[tid + 256 * k] = W4[tid + 256 * k];
        if (tid < 2 * FOUT) sA[tid] = ag[tid];
        const float4* h4 = (const float4*)hp;
        #pragma unroll
        for (int k = 0; k < 8; ++k) {
            int idx = tid + 256 * k;          // float4 index in [0,2048)
            float4 v = h4[idx];
            int row = idx >> 4;               // 16 float4 per 64-float row
            int f   = (idx & 15) << 2;
            sHT[(f + 0) * HT_S + row] = f2bf(v.x);
            sHT[(f + 1) * HT_S + row] = f2bf(v.y);
            sHT[(f + 2) * HT_S + row] = f2bf(v.z);
            sHT[(f + 3) * HT_S + row] = f2bf(v.w);
        }
    }
    __syncthreads();

    // ---------------- phase A: Wh = h @ W, 4x8 register tile ----------------
    const int rg = tid >> 3;      // 0..31 (4 rows each)
    const int cg = tid & 7;       // 0..7  (8 cols each)
    float acc[4][8];
    #pragma unroll
    for (int r = 0; r < 4; ++r)
        #pragma unroll
        for (int c = 0; c < 8; ++c) acc[r][c] = 0.f;

    for (int f = 0; f < FIN; ++f) {
        uint2 hraw = *(const uint2*)&sHT[f * HT_S + rg * 4];
        float hr[4] = { BFLO(hraw.x), BFHI(hraw.x), BFLO(hraw.y), BFHI(hraw.y) };
        float4 w0 = *(const float4*)&sP[f * 64 + cg * 8];
        float4 w1 = *(const float4*)&sP[f * 64 + cg * 8 + 4];
        float wc[8] = {w0.x, w0.y, w0.z, w0.w, w1.x, w1.y, w1.z, w1.w};
        #pragma unroll
        for (int r = 0; r < 4; ++r)
            #pragma unroll
            for (int c = 0; c < 8; ++c)
                acc[r][c] += hr[r] * wc[c];
    }
    __syncthreads();   // all hT/W reads complete before sHT is overwritten

    // write Wh bf16 into sHT ([row][o], stride 64 ushorts), overwriting hT
    #pragma unroll
    for (int r = 0; r < 4; ++r) {
        uint4 u;
        u.x = pack2(acc[r][0], acc[r][1]);
        u.y = pack2(acc[r][2], acc[r][3]);
        u.z = pack2(acc[r][4], acc[r][5]);
        u.w = pack2(acc[r][6], acc[r][7]);
        *(uint4*)&sHT[(rg * 4 + r) * 64 + cg * 8] = u;
    }
    __syncthreads();

    // ---------------- phase B: e_i, e_j from bf16 Wh (full o in [0,64)) ----------------
    if (tid < D_) {
        float ei = 0.f, ej = 0.f;
        #pragma unroll
        for (int q = 0; q < 8; ++q) {
            uint4 wv = *(const uint4*)&sHT[tid * 64 + q * 8];   // 8 bf16: o = q*8 .. q*8+7
            float w0 = BFLO(wv.x), w1 = BFHI(wv.x), w2 = BFLO(wv.y), w3 = BFHI(wv.y);
            float w4 = BFLO(wv.z), w5 = BFHI(wv.z), w6 = BFLO(wv.w), w7 = BFHI(wv.w);
            float4 c1a = *(const float4*)&sA[q * 8];
            float4 c1b = *(const float4*)&sA[q * 8 + 4];
            float4 c2a = *(const float4*)&sA[FOUT + q * 8];
            float4 c2b = *(const float4*)&sA[FOUT + q * 8 + 4];
            ei += w0 * c1a.x + w1 * c1a.y + w2 * c1a.z + w3 * c1a.w
                + w4 * c1b.x + w5 * c1b.y + w6 * c1b.z + w7 * c1b.w;
            ej += w0 * c2a.x + w1 * c2a.y + w2 * c2a.z + w3 * c2a.w
                + w4 * c2b.x + w5 * c2b.y + w6 * c2b.z + w7 * c2b.w;
        }
        sEi[tid] = ei;
        sEj[tid] = ej;
        sL[tid]  = 0.f;
    }
    __syncthreads();

    // ---------------- phase C: masked-softmax @ Wh, tiled over j ----------------
    #pragma unroll
    for (int r = 0; r < 4; ++r)
        #pragma unroll
        for (int c = 0; c < 8; ++c) acc[r][c] = 0.f;

    const int pi = tid >> 1;            // row for p-build
    const int pjb = (tid & 1) << 4;     // 16-j segment within tile

    for (int t4 = 0; t4 < 4; ++t4) {
        const int j0 = t4 * 32;
        // build P-tile: sP[j'][row], j' in [0,32)
        {
            const float ei = sEi[pi];
            float lp = 0.f;
            const int4* arow = (const int4*)&adjp[pi * D_ + j0 + pjb];
            #pragma unroll
            for (int q = 0; q < 4; ++q) {
                int4 av = arow[q];
                int aa[4] = {av.x, av.y, av.z, av.w};
                #pragma unroll
                for (int k = 0; k < 4; ++k) {
                    int j = pjb + q * 4 + k;                 // local j' in [0,32)
                    float e = ei + sEj[j0 + j];
                    e = e > 0.f ? e : ALPHA * e;
                    float p = (aa[k] > 0) ? __expf(e) : 0.f;
                    sP[j * 128 + pi] = p;
                    lp += p;
                }
            }
            lp += __shfl_xor(lp, 1);
            if ((tid & 1) == 0) sL[pi] += lp;
        }
        __syncthreads();
        // accumulate: acc[r][c] += P[jj][rg*4+r] * Wh[j0+jj][cg*8+c]
        for (int jj = 0; jj < 32; ++jj) {
            uint4 wr = *(const uint4*)&sHT[(j0 + jj) * 64 + cg * 8];
            float wc[8] = { BFLO(wr.x), BFHI(wr.x), BFLO(wr.y), BFHI(wr.y),
                            BFLO(wr.z), BFHI(wr.z), BFLO(wr.w), BFHI(wr.w) };
            float4 pv = *(const float4*)&sP[jj * 128 + rg * 4];
            float pr[4] = {pv.x, pv.y, pv.z, pv.w};
            #pragma unroll
            for (int r = 0; r < 4; ++r)
                #pragma unroll
                for (int c = 0; c < 8; ++c)
                    acc[r][c] += pr[r] * wc[c];
        }
        __syncthreads();
    }

    // ---------------- epilogue: divide by row sum, write out ----------------
    #pragma unroll
    for (int r = 0; r < 4; ++r) {
        float inv = 1.0f / sL[rg * 4 + r];
        float4 v0 = make_float4(acc[r][0] * inv, acc[r][1] * inv,
                                acc[r][2] * inv, acc[r][3] * inv);
        float4 v1 = make_float4(acc[r][4] * inv, acc[r][5] * inv,
                                acc[r][6] * inv, acc[r][7] * inv);
        *(float4*)&outp[(rg * 4 + r) * 64 + cg * 8]     = v0;
        *(float4*)&outp[(rg * 4 + r) * 64 + cg * 8 + 4] = v1;
    }
}

extern "C" void kernel_launch(void* const* d_in, const int* in_sizes, int n_in,
                              void* d_out, int out_size, void* d_ws, size_t ws_size,
                              hipStream_t stream) {
    const float* h   = (const float*)d_in[0];
    const int*   adj = (const int*)d_in[1];
    const float* W   = (const float*)d_in[2];
    const float* a   = (const float*)d_in[3];
    float*       out = (float*)d_out;
    gat_kernel<<<dim3(16 * 256), dim3(256), 0, stream>>>(h, adj, W, a, out);
}